// Round 2
// baseline (512.643 us; speedup 1.0000x reference)
//
#include <hip/hip_runtime.h>

// EMA: sta_t = sta_{t-1} + 0.6*(x_t - sta_{t-1}), over T axis of [4096,6000,3] f32.
//
// R2 (505us total): chunk=48ts/lane, LDS transpose for 64B-granule stores.
// R3 counters: top-5 dispatches are all harness fills (~183us each); ema_kernel
// itself ~138us vs ~93us BW floor. Occupancy was LDS-capped at 3 blocks/CU
// (53KB) and 6 block-wide barriers coupled waves that share no LDS.
// R3 changes (numerics bit-identical):
//   - half-slice staging: 32 lanes/round -> LDS 26,624B/block -> 4+ blocks/CU
//   - __launch_bounds__(256,4): VGPR<=128 -> 16 waves/CU (was 12)
//   - all LDS comm is intra-wave -> wave-local lgkmcnt fences, no __syncthreads
// R4: resubmit of R3 unchanged — R3 bench died with a container-level infra
//     error (no counters, no verification result). Kernel re-audited: bounds
//     exact (max f4 idx 18,431,999 < 18,432,000), no hangable constructs.

constexpr float EW = 0.6f;
constexpr int NC_ROW = 125;   // chunks per row = 6000/48
constexpr int PITCH  = 13;    // float4 pitch per LDS slice (12 data + 1 pad)

// accumulate EMA over 3 float4 = 4 timesteps; channels cycle 0,1,2
#define ACC3(v0,v1,v2) do{ \
  a0 += EW*((v0).x-a0); a1 += EW*((v0).y-a1); a2 += EW*((v0).z-a2); \
  a0 += EW*((v0).w-a0); a1 += EW*((v1).x-a1); a2 += EW*((v1).y-a2); \
  a0 += EW*((v1).z-a0); a1 += EW*((v1).w-a1); a2 += EW*((v2).x-a2); \
  a0 += EW*((v2).y-a0); a1 += EW*((v2).z-a1); a2 += EW*((v2).w-a2); \
}while(0)

// same but writes outputs in place
#define STEP3(v0,v1,v2) do{ \
  s0 += EW*((v0).x-s0); (v0).x=s0; s1 += EW*((v0).y-s1); (v0).y=s1; s2 += EW*((v0).z-s2); (v0).z=s2; \
  s0 += EW*((v0).w-s0); (v0).w=s0; s1 += EW*((v1).x-s1); (v1).x=s1; s2 += EW*((v1).y-s2); (v1).y=s2; \
  s0 += EW*((v1).z-s0); (v1).z=s0; s1 += EW*((v1).w-s1); (v1).w=s1; s2 += EW*((v2).x-s2); (v2).x=s2; \
  s0 += EW*((v2).y-s0); (v2).y=s0; s1 += EW*((v2).z-s1); (v2).z=s1; s2 += EW*((v2).w-s2); (v2).w=s2; \
}while(0)

__device__ __forceinline__ void lds_fence() {
    // Wave-local LDS drain. All LDS traffic in this kernel is intra-wave
    // (lanes of a wave exchange within the wave's own slice), so a full
    // __syncthreads is not needed -- just complete outstanding ds ops.
    // volatile + "memory" clobber stops compiler-level reordering of the
    // ds_write/ds_read across the wait; sched_barrier pins the schedule
    // (guide rule #18).
    asm volatile("s_waitcnt lgkmcnt(0)" ::: "memory");
    __builtin_amdgcn_sched_barrier(0);
}

__global__ __launch_bounds__(256, 4) void ema_kernel(const float* __restrict__ x,
                                                     float* __restrict__ y) {
    // one 32-slice buffer per wave: 32*13*16B = 6,656B; 4 waves = 26,624B/block
    __shared__ float4 lds[4][32 * PITCH];
    const int wave = threadIdx.x >> 6;
    const int lane = threadIdx.x & 63;
    const int w    = blockIdx.x * 4 + wave;        // wave id, 0..7999
    const int c    = w * 64 + lane;                // global chunk id, 0..511999
    const int cmod = c % NC_ROW;                   // 0 => chunk starts a row

    const float4* __restrict__ xf = (const float4*)x;
    float4*       __restrict__ yf = (float4*)y;
    const size_t base = (size_t)w * 2304 + (size_t)lane * 36;  // float4 units

    // ---- load own tail (ts 32..48 of chunk) = tile-2 data, reused later
    float4 t0,t1,t2,t3,t4,t5,t6,t7,t8,t9,t10,t11;
    {
        const float4* p = xf + base + 24;
        t0=p[0]; t1=p[1]; t2=p[2]; t3=p[3]; t4=p[4]; t5=p[5];
        t6=p[6]; t7=p[7]; t8=p[8]; t9=p[9]; t10=p[10]; t11=p[11];
    }
    float a0=0.f, a1=0.f, a2=0.f;
    ACC3(t0,t1,t2); ACC3(t3,t4,t5); ACC3(t6,t7,t8); ACC3(t9,t10,t11);

    // neighbor's warm-up init (window W=16, err ~0.4^16)
    float i0 = __shfl_up(a0,1), i1 = __shfl_up(a1,1), i2 = __shfl_up(a2,1);
    if (lane == 0 && cmod != 0) {
        const float4* p = xf + base - 12;          // 16 ts before my chunk
        float4 u0=p[0],u1=p[1],u2=p[2],u3=p[3],u4=p[4],u5=p[5],
               u6=p[6],u7=p[7],u8=p[8],u9=p[9],u10=p[10],u11=p[11];
        a0=0.f; a1=0.f; a2=0.f;
        ACC3(u0,u1,u2); ACC3(u3,u4,u5); ACC3(u6,u7,u8); ACC3(u9,u10,u11);
        i0=a0; i1=a1; i2=a2;
    }
    if (cmod == 0) { i0=0.f; i1=0.f; i2=0.f; }     // exact at row start

    float s0=i0, s1=i1, s2=i2;
    float4* Lw = &lds[wave][0];
    const int g    = lane & 3;     // float4 within 64B granule
    const int sb   = lane >> 2;    // slice-pair selector, 0..15
    const int half = lane >> 5;    // which staging round I write in
    const int lrow = lane & 31;    // my slot within the half-slice buffer

    #pragma unroll
    for (int j = 0; j < 3; ++j) {
        float4 v0,v1,v2,v3,v4,v5,v6,v7,v8,v9,v10,v11;
        if (j == 2) {
            v0=t0;v1=t1;v2=t2;v3=t3;v4=t4;v5=t5;
            v6=t6;v7=t7;v8=t8;v9=t9;v10=t10;v11=t11;
        } else {
            const float4* p = xf + base + j*12;
            v0=p[0];v1=p[1];v2=p[2];v3=p[3];v4=p[4];v5=p[5];
            v6=p[6];v7=p[7];v8=p[8];v9=p[9];v10=p[10];v11=p[11];
        }
        STEP3(v0,v1,v2); STEP3(v3,v4,v5); STEP3(v6,v7,v8); STEP3(v9,v10,v11);

        // two staging rounds: 32 slices at a time through the half-size buffer
        #pragma unroll
        for (int r = 0; r < 2; ++r) {
            if (half == r) {       // my round: stage my 192B slice
                float4* d = Lw + lrow*PITCH;
                d[0]=v0; d[1]=v1; d[2]=v2;  d[3]=v3; d[4]=v4;  d[5]=v5;
                d[6]=v6; d[7]=v7; d[8]=v8;  d[9]=v9; d[10]=v10; d[11]=v11;
            }
            lds_fence();           // RAW: staged slices visible to whole wave
            // all 64 lanes drain 32 slices: 6 store insts, each 16 full
            // 64B granules (global f4 = (r*32+2sb+h)*36 + j*12 + 4i + g)
            #pragma unroll
            for (int h = 0; h < 2; ++h) {
                const int s = sb*2 + h;            // local slice 0..31
                #pragma unroll
                for (int i = 0; i < 3; ++i) {
                    float4 d = Lw[s*PITCH + i*4 + g];
                    yf[(size_t)w*2304 + (size_t)(r*32 + s)*36 + j*12 + i*4 + g] = d;
                }
            }
            lds_fence();           // WAR: reads in regs before slots reused
        }
    }
}

extern "C" void kernel_launch(void* const* d_in, const int* in_sizes, int n_in,
                              void* d_out, int out_size, void* d_ws, size_t ws_size,
                              hipStream_t stream) {
    const float* x = (const float*)d_in[0];
    float* y = (float*)d_out;
    // 512,000 chunks / 64 = 8000 waves / 4 = 2000 blocks
    ema_kernel<<<2000, 256, 0, stream>>>(x, y);
}

// Round 4
// 469.376 us; speedup vs baseline: 1.0922x; 1.0922x over previous
//
#include <hip/hip_runtime.h>

// EMA: sta_t = sta_{t-1} + 0.6*(x_t - sta_{t-1}), over T axis of [4096,6000,3] f32.
//
// R5 redesign. History: R2 (505us) chunk=48ts, scattered per-instr global access
// (576B lane-stride loads, 1152B-stride granule stores via LDS transpose).
// R3/R4 (512us): occupancy bump was NULL -> not latency-limited; forced
// launch_bounds(256,4) likely spilled (144+ live VGPRs). Reverted.
// ema ~140us vs 94us BW floor while fills/D2D hit 6.3-6.4 TB/s -> theory:
// per-instruction lane scatter costs stream efficiency. This version makes
// BOTH streams fill-like: every global instruction is 1KB contiguous.
// R6: byte-identical resubmit of R5 — bench died with the same container-level
//     infra error as R1 (which passed on unmodified resubmit in R2; that run's
//     timing showed a 50-min npz push, i.e. degraded infra). Kernel re-audited:
//     bounds exact, global_load_lds dest wave-uniform, no hangable constructs.
//
//   chunk = 12 ts = 9 float4; wave region = 64 chunks = 576 f4 = 9,216B.
//   stage in: 9x global_load_lds (linear LDS dest, contiguous global)
//   lane reads own chunk at stride 9 f4; EMA in regs; results back to same
//   LDS slots; 9x contiguous 1KB stores.
//   warm-up W=16 by linearity: init(c) = A(c-1) + 0.4^12 * B(c-2),
//     A = EMA-from-0 over full chunk, B = EMA-from-0 over its last 4 ts,
//     via shfl_up(1)/shfl_up(2). m==1 is exact (A alone). Lanes 0/1 load
//     their windows directly (lane0 never has m==1: 64w % 500 != 1).
//   known imperfection (next lever if this validates but lands short):
//     144B-stride LDS chunk access is 8-way bank-conflicted (~15-25us worst
//     case, mostly overlapped with global streams).

constexpr float EW  = 0.6f;
constexpr float D12 = 1.6777216e-05f;   // 0.4^12
constexpr int   NCROW = 500;            // 12-ts chunks per row (6000/12)

// accumulate EMA over 3 float4 = 4 timesteps; channels cycle 0,1,2
#define EMA4(A0,A1,A2,v0,v1,v2) do{ \
  A0 += EW*((v0).x-A0); A1 += EW*((v0).y-A1); A2 += EW*((v0).z-A2); \
  A0 += EW*((v0).w-A0); A1 += EW*((v1).x-A1); A2 += EW*((v1).y-A2); \
  A0 += EW*((v1).z-A0); A1 += EW*((v1).w-A1); A2 += EW*((v2).x-A2); \
  A0 += EW*((v2).y-A0); A1 += EW*((v2).z-A1); A2 += EW*((v2).w-A2); \
}while(0)

// same but writes outputs in place
#define EMA4W(S0,S1,S2,v0,v1,v2) do{ \
  S0 += EW*((v0).x-S0); (v0).x=S0; S1 += EW*((v0).y-S1); (v0).y=S1; S2 += EW*((v0).z-S2); (v0).z=S2; \
  S0 += EW*((v0).w-S0); (v0).w=S0; S1 += EW*((v1).x-S1); (v1).x=S1; S2 += EW*((v1).y-S2); (v1).y=S2; \
  S0 += EW*((v1).z-S0); (v1).z=S0; S1 += EW*((v1).w-S1); (v1).w=S1; S2 += EW*((v2).x-S2); (v2).x=S2; \
  S0 += EW*((v2).y-S0); (v2).y=S0; S1 += EW*((v2).z-S1); (v2).z=S1; S2 += EW*((v2).w-S2); (v2).w=S2; \
}while(0)

__device__ __forceinline__ void lds_fence() {
    // wave-local LDS drain (all LDS comm here is intra-wave)
    asm volatile("s_waitcnt lgkmcnt(0)" ::: "memory");
    __builtin_amdgcn_sched_barrier(0);
}
__device__ __forceinline__ void vm_fence() {
    // drain global_load_lds (vmcnt-tracked) before reading staged LDS
    asm volatile("s_waitcnt vmcnt(0)" ::: "memory");
    __builtin_amdgcn_sched_barrier(0);
}

__global__ __launch_bounds__(256) void ema_kernel(const float* __restrict__ x,
                                                  float* __restrict__ y) {
    __shared__ float4 lds[4][576];                 // 36,864B -> 4 blocks/CU
    const int wave = threadIdx.x >> 6;
    const int lane = threadIdx.x & 63;
    const int w    = blockIdx.x * 4 + wave;        // wave id, 0..31999
    const int c    = w * 64 + lane;                // global chunk id, 0..2047999
    const int m    = c % NCROW;                    // 0 => chunk starts a row

    const float4* __restrict__ xf = (const float4*)x;
    float4*       __restrict__ yf = (float4*)y;
    const size_t base = (size_t)w * 576;           // float4 units
    float4* Lw = &lds[wave][0];

    // ---- aux warm-up loads for lanes 0,1 (issued first; latency overlaps
    //      the staging phase). Window base = 16 ts before my chunk.
    //      lane0: m!=0 => m>=4 (64w%500 is a multiple of 4) -> 12 f4 in bounds.
    //      lane1: m>=2 => m>=5 -> 3 f4 in bounds.
    float4 u0,u1,u2,u3,u4,u5,u6,u7,u8,u9,u10,u11;
    if ((lane == 0 && m != 0) || (lane == 1 && m >= 2)) {
        const float4* p = xf + (size_t)c * 9 - 12;
        u0=p[0]; u1=p[1]; u2=p[2];
        if (lane == 0) {
            u3=p[3]; u4=p[4];  u5=p[5];  u6=p[6]; u7=p[7]; u8=p[8];
            u9=p[9]; u10=p[10]; u11=p[11];
        }
    }

    // ---- stage wave region: 9 contiguous 1KB loads, direct to LDS (linear)
    #pragma unroll
    for (int i = 0; i < 9; ++i) {
        __builtin_amdgcn_global_load_lds(
            (const __attribute__((address_space(1))) void*)(xf + base + i*64 + lane),
            (__attribute__((address_space(3))) void*)(Lw + i*64),
            16, 0, 0);
    }
    vm_fence();                                    // staging + aux complete

    // ---- read own chunk (stride 9 f4)
    float4 c0,c1,c2,c3,c4,c5,c6,c7,c8;
    {
        const float4* q = Lw + lane * 9;
        c0=q[0]; c1=q[1]; c2=q[2]; c3=q[3]; c4=q[4];
        c5=q[5]; c6=q[6]; c7=q[7]; c8=q[8];
    }

    // ---- from-zero EMAs: A over all 12 ts, B over last 4 ts (f4 6..8)
    float a0=0.f,a1=0.f,a2=0.f, b0=0.f,b1=0.f,b2=0.f;
    EMA4(a0,a1,a2,c0,c1,c2); EMA4(a0,a1,a2,c3,c4,c5); EMA4(a0,a1,a2,c6,c7,c8);
    EMA4(b0,b1,b2,c6,c7,c8);

    const float A0=__shfl_up(a0,1), A1=__shfl_up(a1,1), A2=__shfl_up(a2,1);
    const float B0=__shfl_up(b0,2), B1=__shfl_up(b1,2), B2=__shfl_up(b2,2);

    float i0,i1,i2;
    if (m == 0)      { i0=0.f; i1=0.f; i2=0.f; }                    // exact
    else if (m == 1) { i0=A0;  i1=A1;  i2=A2;  }                    // exact
    else             { i0=A0+D12*B0; i1=A1+D12*B1; i2=A2+D12*B2; }  // W=16

    if (lane == 0 && m != 0) {      // no left neighbor: own 16-ts window
        float w0=0.f,w1=0.f,w2=0.f;
        EMA4(w0,w1,w2,u0,u1,u2);  EMA4(w0,w1,w2,u3,u4,u5);
        EMA4(w0,w1,w2,u6,u7,u8);  EMA4(w0,w1,w2,u9,u10,u11);
        i0=w0; i1=w1; i2=w2;
    }
    if (lane == 1 && m >= 2) {      // B window loaded directly; A via shfl
        float z0=0.f,z1=0.f,z2=0.f;
        EMA4(z0,z1,z2,u0,u1,u2);
        i0 = A0 + D12*z0; i1 = A1 + D12*z1; i2 = A2 + D12*z2;
    }

    // ---- main EMA over my 12 ts, results in place
    EMA4W(i0,i1,i2,c0,c1,c2); EMA4W(i0,i1,i2,c3,c4,c5); EMA4W(i0,i1,i2,c6,c7,c8);

    // ---- results to LDS (same slots), then contiguous 1KB stores
    {
        float4* q = Lw + lane * 9;
        q[0]=c0; q[1]=c1; q[2]=c2; q[3]=c3; q[4]=c4;
        q[5]=c5; q[6]=c6; q[7]=c7; q[8]=c8;
    }
    lds_fence();                                   // cross-lane RAW
    #pragma unroll
    for (int i = 0; i < 9; ++i) {
        yf[base + i*64 + lane] = Lw[i*64 + lane];  // 16 full 64B granules/instr
    }
}

extern "C" void kernel_launch(void* const* d_in, const int* in_sizes, int n_in,
                              void* d_out, int out_size, void* d_ws, size_t ws_size,
                              hipStream_t stream) {
    const float* x = (const float*)d_in[0];
    float* y = (float*)d_out;
    // 2,048,000 chunks / 64 = 32,000 waves / 4 = 8,000 blocks
    ema_kernel<<<8000, 256, 0, stream>>>(x, y);
}